// Round 5
// baseline (80.912 us; speedup 1.0000x reference)
//
#include <hip/hip_runtime.h>
#include <math.h>

#define MROWS 32768   // B*T
#define DDIM  1024
#define EDIM  64
#define NCH   64      // K-chunks of 16
#define TILEM 128     // rows per block = 4 waves x 32

typedef _Float16 f16x8 __attribute__((ext_vector_type(8)));
typedef float    f32x16 __attribute__((ext_vector_type(16)));

// ws layout per chunk c (4096 halves = 8 KB), B-frag-linear (verified R4):
//   half index = c*4096 + p*2048 + nf*512 + lane*8 + j
//   B frag (32x32x16): col = nf*32 + (lane&31), k = (lane>>5)*8 + j
__global__ __launch_bounds__(256)
void convW_kernel(const float* __restrict__ Wr, const float* __restrict__ Wn,
                  unsigned short* __restrict__ ws) {
    int gid = blockIdx.x * 256 + threadIdx.x;   // 131072 total
    int c32 = gid & 31;
    int j   = (gid >> 5) & 7;
    int lhi = (gid >> 8) & 1;
    int nf  = (gid >> 9) & 3;
    int c   = gid >> 11;
    int lane = lhi * 32 + c32;
    int k   = c * 16 + lhi * 8 + j;
    int col = nf * 32 + c32;                    // 0..63 route, 64..127 noise
    float w = (col < EDIM) ? Wr[k * EDIM + col] : Wn[k * EDIM + (col - EDIM)];
    _Float16 hi = (_Float16)w;
    _Float16 lo = (_Float16)((w - (float)hi) * 2048.0f);
    union { _Float16 h; unsigned short u; } cv;
    size_t base = (size_t)c * 4096 + nf * 512 + lane * 8 + j;
    cv.h = hi; ws[base]        = cv.u;
    cv.h = lo; ws[base + 2048] = cv.u;
}

__global__ __launch_bounds__(256, 1)
void router_mfma(const float* __restrict__ X,
                 const unsigned short* __restrict__ WS,
                 const float* __restrict__ br_g,
                 const float* __restrict__ bn_g,
                 const float* __restrict__ U,
                 float* __restrict__ out)
{
    __shared__ unsigned short Bh[2][4096];   // 16 KB double buffer

    const int t    = threadIdx.x;
    const int lane = t & 63;
    const int wid  = __builtin_amdgcn_readfirstlane(t >> 6);   // 0..3
    const int rowBase = blockIdx.x * TILEM;
    const int myRow = rowBase + wid * 32 + (lane & 31);
    const int kSub  = (lane >> 5) * 8;       // 0 or 8
    const float* xp = X + (size_t)myRow * DDIM + kSub;
    const char* wsB = (const char*)WS;

    f32x16 acc0[4], acc1[4];
#pragma unroll
    for (int nf = 0; nf < 4; ++nf)
#pragma unroll
        for (int i = 0; i < 16; ++i) { acc0[nf][i] = 0.f; acc1[nf][i] = 0.f; }

    // stage B chunk c into Bh[buf]: linear 8 KB, 2 rounds x (64 lanes x 16B) per wave
    auto stageB = [&](int c, int buf) {
#pragma unroll
        for (int r = 0; r < 2; ++r) {
            int o = r * 4096 + wid * 1024;
            __builtin_amdgcn_global_load_lds(
                (const __attribute__((address_space(1))) void*)(wsB + (size_t)c * 8192 + o + lane * 16),
                (__attribute__((address_space(3))) void*)((char*)&Bh[buf][0] + o),
                16, 0, 0);
        }
    };

    auto convA8 = [&](const float4& a, const float4& b, f16x8& hi, f16x8& lo) {
        float x[8] = {a.x, a.y, a.z, a.w, b.x, b.y, b.z, b.w};
#pragma unroll
        for (int j = 0; j < 8; ++j) {
            _Float16 h = (_Float16)x[j];
            hi[j] = h;
            lo[j] = (_Float16)((x[j] - (float)h) * 2048.0f);
        }
    };

    auto compute = [&](int buf, const f16x8& ahi, const f16x8& alo) {
        const unsigned short* Bb = &Bh[buf][0];
#pragma unroll
        for (int nf = 0; nf < 4; ++nf) {
            f16x8 bhi = *(const f16x8*)(Bb + nf * 512 + lane * 8);
            f16x8 blo = *(const f16x8*)(Bb + 2048 + nf * 512 + lane * 8);
            acc0[nf] = __builtin_amdgcn_mfma_f32_32x32x16_f16(ahi, bhi, acc0[nf], 0, 0, 0);
            acc1[nf] = __builtin_amdgcn_mfma_f32_32x32x16_f16(ahi, blo, acc1[nf], 0, 0, 0);
            acc1[nf] = __builtin_amdgcn_mfma_f32_32x32x16_f16(alo, bhi, acc1[nf], 0, 0, 0);
        }
    };

    // ---- prologue ----
    stageB(0, 0);
    float4 xA0 = *(const float4*)(xp);
    float4 xA1 = *(const float4*)(xp + 4);
    float4 xB0 = *(const float4*)(xp + 16);
    float4 xB1 = *(const float4*)(xp + 20);
    __syncthreads();   // drains stageB(0)

    for (int c = 0; c < NCH; c += 2) {
        // ---- even chunk c (buf 0) ----
        if (c + 1 < NCH) stageB(c + 1, 1);
        {
            f16x8 ahi, alo;
            convA8(xA0, xA1, ahi, alo);
            if (c + 2 < NCH) {
                xA0 = *(const float4*)(xp + (c + 2) * 16);
                xA1 = *(const float4*)(xp + (c + 2) * 16 + 4);
            }
            compute(0, ahi, alo);
        }
        __syncthreads();
        // ---- odd chunk c+1 (buf 1) ----
        if (c + 2 < NCH) stageB(c + 2, 0);
        {
            f16x8 ahi, alo;
            convA8(xB0, xB1, ahi, alo);
            if (c + 3 < NCH) {
                xB0 = *(const float4*)(xp + (c + 3) * 16);
                xB1 = *(const float4*)(xp + (c + 3) * 16 + 4);
            }
            compute(1, ahi, alo);
        }
        __syncthreads();
    }

    // ---- epilogue: fully in-wave (no LDS) ----
    const int c0 = lane & 31;
    const float br0 = br_g[c0],      br1 = br_g[32 + c0];
    const float bn0 = bn_g[c0],      bn1 = bn_g[32 + c0];
    const int rBase2 = rowBase + wid * 32 + 4 * (lane >> 5);
    const float inv2048 = 1.0f / 2048.0f;

#pragma unroll
    for (int reg = 0; reg < 16; ++reg) {
        int grow = rBase2 + (reg & 3) + 8 * (reg >> 2);
        float v0 = acc0[0][reg] + acc1[0][reg] * inv2048;   // route col c0
        float v1 = acc0[1][reg] + acc1[1][reg] * inv2048;   // route col c0+32
        float v2 = acc0[2][reg] + acc1[2][reg] * inv2048;   // noise col c0
        float v3 = acc0[3][reg] + acc1[3][reg] * inv2048;   // noise col c0+32
        float u0 = U[(size_t)grow * EDIM + c0];
        float u1 = U[(size_t)grow * EDIM + 32 + c0];
        float n0 = (v0 + br0) + u0 * log1pf(expf(v2 + bn0));
        float n1 = (v1 + br1) + u1 * log1pf(expf(v3 + bn1));

        float m1, m2; int i1, i2;
        if (n0 >= n1) { m1 = n0; i1 = c0;      m2 = n1; i2 = 32 + c0; }
        else          { m1 = n1; i1 = 32 + c0; m2 = n0; i2 = c0;      }
#pragma unroll
        for (int s = 1; s < 32; s <<= 1) {     // stays within 32-lane half
            float om1 = __shfl_xor(m1, s); int oi1 = __shfl_xor(i1, s);
            float om2 = __shfl_xor(m2, s); int oi2 = __shfl_xor(i2, s);
            bool aw = (m1 > om1) || (m1 == om1 && i1 < oi1);
            float w1  = aw ? m1 : om1;  int wi1  = aw ? i1 : oi1;
            float c2a = aw ? m2 : om2;  int c2ai = aw ? i2 : oi2;
            float c2b = aw ? om1 : m1;  int c2bi = aw ? oi1 : i1;
            bool bw = (c2b > c2a) || (c2b == c2a && c2bi < c2ai);
            m1 = w1; i1 = wi1;
            m2 = bw ? c2b : c2a;
            i2 = bw ? c2bi : c2ai;
        }
        float e2  = expf(m2 - m1);
        float inv = 1.0f / (1.0f + e2);
        float P1 = inv, P2 = e2 * inv;
        float p0 = (i1 == c0)      ? P1 : ((i2 == c0)      ? P2 : 0.0f);
        float p1 = (i1 == 32 + c0) ? P1 : ((i2 == 32 + c0) ? P2 : 0.0f);
        out[(size_t)grow * EDIM + c0]      = p0;
        out[(size_t)grow * EDIM + 32 + c0] = p1;
        if (c0 < 2)
            out[(size_t)MROWS * EDIM + (size_t)grow * 2 + c0] =
                (float)(c0 == 0 ? i1 : i2);
    }
}

extern "C" void kernel_launch(void* const* d_in, const int* in_sizes, int n_in,
                              void* d_out, int out_size, void* d_ws, size_t ws_size,
                              hipStream_t stream) {
    const float* X  = (const float*)d_in[0];  // mh_output [8,4096,1024]
    const float* Wr = (const float*)d_in[1];  // W_route   [1024,64]
    const float* br = (const float*)d_in[2];  // b_route   [64]
    const float* Wn = (const float*)d_in[3];  // W_noise   [1024,64]
    const float* bn = (const float*)d_in[4];  // b_noise   [64]
    const float* U  = (const float*)d_in[5];  // noise_u   [8,4096,64]
    (void)in_sizes; (void)n_in; (void)ws_size; // uses 512 KB of d_ws
    unsigned short* ws16 = (unsigned short*)d_ws;
    convW_kernel<<<512, 256, 0, stream>>>(Wr, Wn, ws16);
    router_mfma<<<MROWS / TILEM, 256, 0, stream>>>(X, ws16, br, bn, U, (float*)d_out);
}